// Round 1
// baseline (429.074 us; speedup 1.0000x reference)
//
#include <hip/hip_runtime.h>
#include <stdint.h>

// Problem constants
#define NBATCH 2
#define NVERT  30000
#define VOLCH  16777216ull   // 64^3 * 64 elements per batch, layout (z,y,x,c)
#define KDIM   1728          // 27 * 64
#define ASTR   (KDIM + 8)    // +8 bf16 pad -> conflict-free ds_read_b128

typedef __attribute__((ext_vector_type(8))) __bf16 bf16x8;
typedef __attribute__((ext_vector_type(4))) float f32x4;

__device__ __forceinline__ float b2f(unsigned short u) {
  unsigned int x = ((unsigned int)u) << 16;
  return __builtin_bit_cast(float, x);
}

__device__ __forceinline__ unsigned short f2b(float f) {
  unsigned int u = __builtin_bit_cast(unsigned int, f);
  u = (u + 0x7FFFu + ((u >> 16) & 1u)) >> 16;   // RNE (no NaN in this data)
  return (unsigned short)u;
}

// ---------------------------------------------------------------------------
// Kernel 1: transpose volume (b,c,z,y,x) f32 -> (b,z,y,x,c) bf16 in d_ws.
// Makes per-vertex channel gathers fully coalesced (128B per voxel).
// ---------------------------------------------------------------------------
__global__ __launch_bounds__(256) void transpose_vox(
    const float* __restrict__ vox, unsigned short* __restrict__ T) {
  __shared__ float tile[64][65];                // +1 pad: conflict-free both ways
  const int b = blockIdx.y;
  const int zy = blockIdx.x;                    // z*64 + y
  const size_t src0 = (size_t)b * 64 * 262144 + (size_t)zy * 64;
#pragma unroll
  for (int i = 0; i < 16; ++i) {
    int idx = i * 256 + threadIdx.x;
    int c = idx >> 6, x = idx & 63;             // read x-major: coalesced 256B
    tile[c][x] = vox[src0 + (size_t)c * 262144 + x];
  }
  __syncthreads();
  const size_t dst0 = ((size_t)b * 4096 + zy) * 4096;
#pragma unroll
  for (int i = 0; i < 16; ++i) {
    int idx = i * 256 + threadIdx.x;
    int x = idx >> 6, c = idx & 63;             // write c-major: coalesced 128B
    T[dst0 + x * 64 + c] = f2b(tile[c][x]);
  }
}

// ---------------------------------------------------------------------------
// Kernel 2: pack conv_w (o,c,k) f32 -> fragment-major bf16 W3[K>>3][o][K&7],
// K = k*64 + c. B-fragment of mfma_16x16x32 is then one contiguous 16B load.
// ---------------------------------------------------------------------------
__global__ __launch_bounds__(256) void prep_w(
    const float* __restrict__ w, unsigned short* __restrict__ W3) {
  int t = blockIdx.x * 256 + threadIdx.x;       // 432*256 == 110592 exactly
  int o = t / 1728;
  int rem = t - o * 1728;
  int c = rem / 27;
  int k = rem - c * 27;
  int K = k * 64 + c;
  W3[((size_t)(K >> 3) * 64 + o) * 8 + (K & 7)] = f2b(w[t]);
}

// ---------------------------------------------------------------------------
// Per-axis setup: region indices idx[0..3] = clamp(b0-1+p) and dense shift
// weights gw[d][p] (sum of the two trilinear taps that land on region pos p,
// clamp-aware). Dense table avoids runtime-indexed register arrays (rule #20).
// ---------------------------------------------------------------------------
__device__ __forceinline__ void axis_setup(float v, int idx[4], float gw[3][4]) {
  float coord = (v + 1.0f) * 0.5f * 63.0f;
  coord = fminf(fmaxf(coord, 0.0f), 63.0f);
  int b0 = (int)coord;
  if (b0 > 63) b0 = 63;
#pragma unroll
  for (int p = 0; p < 4; ++p) {
    int q = b0 - 1 + p;
    idx[p] = min(max(q, 0), 63);
  }
#pragma unroll
  for (int d = 0; d < 3; ++d) {
    float t = coord + (float)(d - 1);           // shifts are exactly +-1 voxel
    float tc = fminf(fmaxf(t, 0.0f), 63.0f);
    float fl = floorf(tc);
    int i0 = (int)fl;
    if (i0 > 63) i0 = 63;
    float f = tc - fl;
    int i1 = min(i0 + 1, 63);
    int p0 = i0 - b0 + 1;                       // provably in [0,3]
    int p1 = i1 - b0 + 1;
#pragma unroll
    for (int p = 0; p < 4; ++p) {
      float g = (p == p0) ? (1.0f - f) : 0.0f;
      g += (p == p1) ? f : 0.0f;
      gw[d][p] = g;
    }
  }
}

// ---------------------------------------------------------------------------
// Kernel 3 (fused): gather 16 vertices' feats (bf16) into LDS, then
// 16x64 = A(16x1728) * W3(1728x64) via mfma_f32_16x16x32_bf16.
// Block: 256 threads / 4 waves. Wave w gathers vertices w*4..w*4+3
// (lane = channel), then computes output n-tile o = w*16..w*16+15.
// ---------------------------------------------------------------------------
__global__ __launch_bounds__(256, 2) void fused_main(
    const float* __restrict__ verts, const unsigned short* __restrict__ T,
    const unsigned short* __restrict__ W3, const float* __restrict__ bias,
    float* __restrict__ out) {
  __shared__ __align__(16) unsigned short A_lds[16][ASTR];
  const int tid = threadIdx.x;
  const int wave = tid >> 6;
  const int lane = tid & 63;
  const int batch = blockIdx.y;
  const int n0 = blockIdx.x * 16;

  const unsigned short* Tb = T + (size_t)batch * VOLCH + lane;  // lane = channel

  // ---- phase 1: gather + separable trilinear fold ----
#pragma unroll 1
  for (int vl = 0; vl < 4; ++vl) {
    const int m = wave * 4 + vl;
    const size_t vbase = ((size_t)batch * NVERT + (n0 + m)) * 3;
    const float vx = verts[vbase + 0];
    const float vy = verts[vbase + 1];
    const float vz = verts[vbase + 2];

    int xi[4], yi[4], zi[4];
    float gwx[3][4], gwy[3][4], gwz[3][4];
    axis_setup(vx, xi, gwx);
    axis_setup(vy, yi, gwy);
    axis_setup(vz, zi, gwz);

    int xo[4];
#pragma unroll
    for (int p = 0; p < 4; ++p) xo[p] = xi[p] << 6;   // *64 channels

    float fe[3][3][3];
#pragma unroll
    for (int a = 0; a < 3; ++a)
#pragma unroll
      for (int bb = 0; bb < 3; ++bb)
#pragma unroll
        for (int cc = 0; cc < 3; ++cc) fe[a][bb][cc] = 0.0f;

#pragma unroll
    for (int pz = 0; pz < 4; ++pz) {
      float ryv[3][3];
#pragma unroll
      for (int a = 0; a < 3; ++a)
#pragma unroll
        for (int bb = 0; bb < 3; ++bb) ryv[a][bb] = 0.0f;
      const int zoff = zi[pz] << 18;                  // *64*64*64
#pragma unroll
      for (int py = 0; py < 4; ++py) {
        const unsigned short* rp = Tb + zoff + (yi[py] << 12);
        float v0 = b2f(rp[xo[0]]);                    // 128B coalesced per voxel
        float v1 = b2f(rp[xo[1]]);
        float v2 = b2f(rp[xo[2]]);
        float v3 = b2f(rp[xo[3]]);
        const float wy0 = gwy[0][py], wy1 = gwy[1][py], wy2 = gwy[2][py];
#pragma unroll
        for (int dx = 0; dx < 3; ++dx) {
          float rx = v0 * gwx[dx][0] + v1 * gwx[dx][1] +
                     v2 * gwx[dx][2] + v3 * gwx[dx][3];
          ryv[0][dx] += rx * wy0;
          ryv[1][dx] += rx * wy1;
          ryv[2][dx] += rx * wy2;
        }
      }
#pragma unroll
      for (int dz = 0; dz < 3; ++dz) {
        const float wz = gwz[dz][pz];
#pragma unroll
        for (int dy = 0; dy < 3; ++dy)
#pragma unroll
          for (int dx = 0; dx < 3; ++dx) fe[dz][dy][dx] += ryv[dy][dx] * wz;
      }
    }

    // write feats, K = k*64 + c with k = dx*9 + dy*3 + dz (product order)
    unsigned short* arow = &A_lds[m][0];
#pragma unroll
    for (int dz = 0; dz < 3; ++dz)
#pragma unroll
      for (int dy = 0; dy < 3; ++dy)
#pragma unroll
        for (int dx = 0; dx < 3; ++dx) {
          int k = dx * 9 + dy * 3 + dz;
          arow[(k << 6) + lane] = f2b(fe[dz][dy][dx]);  // contiguous across lanes
        }
  }
  __syncthreads();

  // ---- phase 2: MFMA GEMM, one 16x16 tile per wave ----
  const int g = lane >> 4;                      // k-group 0..3
  const int r = lane & 15;                      // A-row / B-col index
  const int o0 = wave * 16;
  f32x4 acc = {0.0f, 0.0f, 0.0f, 0.0f};
  const unsigned short* aptr = &A_lds[r][g * 8];
  const unsigned short* bptr = W3 + (size_t)(g * 64 + o0 + r) * 8;
  for (int kk = 0; kk < 54; ++kk) {
    bf16x8 a = *reinterpret_cast<const bf16x8*>(aptr + kk * 32);
    bf16x8 b = *reinterpret_cast<const bf16x8*>(bptr + (size_t)kk * 2048);
    acc = __builtin_amdgcn_mfma_f32_16x16x32_bf16(a, b, acc, 0, 0, 0);
  }

  // epilogue: D col = lane&15 (o), row = (lane>>4)*4 + i (vertex), + bias
  const int oc = o0 + r;
  const float bo = bias[oc];
  float* op = out + ((size_t)batch * NVERT + n0) * 64 + oc;
#pragma unroll
  for (int i = 0; i < 4; ++i) {
    op[(size_t)(g * 4 + i) * 64] = acc[i] + bo;
  }
}

extern "C" void kernel_launch(void* const* d_in, const int* in_sizes, int n_in,
                              void* d_out, int out_size, void* d_ws, size_t ws_size,
                              hipStream_t stream) {
  const float* vox   = (const float*)d_in[0];
  const float* verts = (const float*)d_in[1];
  const float* convw = (const float*)d_in[2];
  const float* convb = (const float*)d_in[3];
  float* out = (float*)d_out;

  const size_t t_elems = (size_t)NBATCH * VOLCH;        // 33,554,432 bf16
  const size_t need = t_elems * 2 + (size_t)110592 * 2; // ~67.3 MB
  if (ws_size < need) {
    // distinguishable sentinel: NaN output => "workspace too small"
    hipMemsetAsync(d_out, 0xFF, (size_t)out_size * 4, stream);
    return;
  }
  unsigned short* T  = (unsigned short*)d_ws;
  unsigned short* W3 = T + t_elems;

  transpose_vox<<<dim3(4096, NBATCH), 256, 0, stream>>>(vox, T);
  prep_w<<<432, 256, 0, stream>>>(convw, W3);
  fused_main<<<dim3(NVERT / 16, NBATCH), 256, 0, stream>>>(verts, T, W3, convb, out);
}